// Round 2
// baseline (1566.782 us; speedup 1.0000x reference)
//
#include <hip/hip_runtime.h>
#include <hip/hip_bf16.h>
#include <math.h>

#define DIMC 768
#define HEADS 12
#define HD 64
#define EXPERTS 8
#define HID 3072
#define BB 8
#define NN 196
#define TT (BB*NN)      // 1568
#define CAP_ROWS 3392   // 2*TT + 8*32 headroom, multiple of 32
#define LN_EPS 1e-5f

// ---------------- LayerNorm: one block per token, 256 threads, D=768 ----------------
__global__ void ln_kernel(const float* __restrict__ x, const float* __restrict__ g,
                          const float* __restrict__ b, float* __restrict__ out) {
    int t = blockIdx.x;
    const float* xr = x + (size_t)t * DIMC;
    int tid = threadIdx.x;
    float v0 = xr[tid], v1 = xr[tid + 256], v2 = xr[tid + 512];
    __shared__ float red[256];
    red[tid] = v0 + v1 + v2;
    __syncthreads();
    for (int off = 128; off > 0; off >>= 1) {
        if (tid < off) red[tid] += red[tid + off];
        __syncthreads();
    }
    float mu = red[0] * (1.0f / DIMC);
    __syncthreads();
    float d0 = v0 - mu, d1 = v1 - mu, d2 = v2 - mu;
    red[tid] = d0*d0 + d1*d1 + d2*d2;
    __syncthreads();
    for (int off = 128; off > 0; off >>= 1) {
        if (tid < off) red[tid] += red[tid + off];
        __syncthreads();
    }
    float rstd = rsqrtf(red[0] * (1.0f / DIMC) + LN_EPS);
    float* o = out + (size_t)t * DIMC;
    o[tid]       = d0 * rstd * g[tid]       + b[tid];
    o[tid + 256] = d1 * rstd * g[tid + 256] + b[tid + 256];
    o[tid + 512] = d2 * rstd * g[tid + 512] + b[tid + 512];
}

// ---------------- generic fp32 tiled GEMM: C = A[M,K] @ B[K,N] + bias (+res) ----------------
// grid (M/32, N/64), block 256. M%32==0, N%64==0, K%32==0 assumed.
__global__ void gemm_f32(const float* __restrict__ A, const float* __restrict__ B,
                         const float* __restrict__ bias, const float* __restrict__ res,
                         float* __restrict__ C, int M, int N, int K) {
    __shared__ float As[32][33];
    __shared__ float Bs[32][65];
    int m0 = blockIdx.x * 32;
    int n0 = blockIdx.y * 64;
    int tid = threadIdx.x;
    int ty = tid / 16, tx = tid % 16;
    float acc[2][4] = {};
    for (int k0 = 0; k0 < K; k0 += 32) {
        {
            int c = tid % 32, rr = tid / 32;
            #pragma unroll
            for (int p = 0; p < 4; ++p) {
                int r = rr + p * 8;
                As[r][c] = A[(size_t)(m0 + r) * K + k0 + c];
            }
        }
        {
            int c = tid % 64, rr = tid / 64;
            #pragma unroll
            for (int p = 0; p < 8; ++p) {
                int r = rr + p * 4;
                Bs[r][c] = B[(size_t)(k0 + r) * N + n0 + c];
            }
        }
        __syncthreads();
        #pragma unroll
        for (int k = 0; k < 32; ++k) {
            float a0 = As[ty*2+0][k];
            float a1 = As[ty*2+1][k];
            #pragma unroll
            for (int j = 0; j < 4; ++j) {
                float bj = Bs[k][tx*4+j];
                acc[0][j] += a0 * bj;
                acc[1][j] += a1 * bj;
            }
        }
        __syncthreads();
    }
    #pragma unroll
    for (int i = 0; i < 2; ++i) {
        int r = m0 + ty*2 + i;
        #pragma unroll
        for (int j = 0; j < 4; ++j) {
            int c = n0 + tx*4 + j;
            float v = acc[i][j] + bias[c];
            if (res) v += res[(size_t)r * N + c];
            C[(size_t)r * N + c] = v;
        }
    }
}

// ---------------- attention: grid (B*H, ceil(N/32)), block 256 ----------------
__global__ void attn_kernel(const float* __restrict__ qkv, float* __restrict__ o) {
    int bh = blockIdx.x;
    int b = bh / HEADS, h = bh % HEADS;
    int i0 = blockIdx.y * 32;
    const float* base = qkv + (size_t)b * NN * 2304;
    __shared__ float qs[32][64];
    __shared__ float ps[32][200];
    int tid = threadIdx.x;
    for (int idx = tid; idx < 32 * 64; idx += 256) {
        int i = idx / 64, d = idx % 64;
        int n = i0 + i;
        qs[i][d] = (n < NN) ? base[(size_t)n * 2304 + h * 64 + d] : 0.f;
    }
    __syncthreads();
    for (int idx = tid; idx < 32 * NN; idx += 256) {
        int i = idx / NN, j = idx % NN;
        const float* kr = base + (size_t)j * 2304 + 768 + h * 64;
        float s = 0.f;
        #pragma unroll
        for (int d = 0; d < 64; ++d) s += qs[i][d] * kr[d];
        ps[i][j] = s * 0.125f;  // hd^-0.5
    }
    __syncthreads();
    {
        int i = tid / 8, l = tid % 8;
        float mx = -1e30f;
        for (int j = l; j < NN; j += 8) mx = fmaxf(mx, ps[i][j]);
        #pragma unroll
        for (int off = 4; off > 0; off >>= 1) mx = fmaxf(mx, __shfl_xor(mx, off, 8));
        float sum = 0.f;
        for (int j = l; j < NN; j += 8) { float e = expf(ps[i][j] - mx); ps[i][j] = e; sum += e; }
        #pragma unroll
        for (int off = 4; off > 0; off >>= 1) sum += __shfl_xor(sum, off, 8);
        float inv = 1.f / sum;
        for (int j = l; j < NN; j += 8) ps[i][j] *= inv;
    }
    __syncthreads();
    for (int idx = tid; idx < 32 * 64; idx += 256) {
        int i = idx / 64, d = idx % 64;
        int n = i0 + i;
        if (n >= NN) continue;
        float s = 0.f;
        for (int j = 0; j < NN; ++j) s += ps[i][j] * base[(size_t)j * 2304 + 1536 + h * 64 + d];
        o[((size_t)(b * NN + n)) * DIMC + h * 64 + d] = s;
    }
}

// ---------------- gate: one wave per token ----------------
__global__ void gate_kernel(const float* __restrict__ xn, const float* __restrict__ gw,
                            int* __restrict__ tok_e, float* __restrict__ tok_g,
                            int* __restrict__ counts) {
    int t = blockIdx.x;
    int lane = threadIdx.x;  // 64
    float acc[8] = {};
    const float* xr = xn + (size_t)t * DIMC;
    for (int i = lane; i < DIMC; i += 64) {
        float xi = xr[i];
        const float* gr = gw + (size_t)i * 8;
        #pragma unroll
        for (int e = 0; e < 8; ++e) acc[e] += xi * gr[e];
    }
    #pragma unroll
    for (int e = 0; e < 8; ++e) {
        #pragma unroll
        for (int off = 32; off > 0; off >>= 1) acc[e] += __shfl_down(acc[e], off, 64);
    }
    if (lane == 0) {
        int e0 = 0; float l0 = acc[0];
        #pragma unroll
        for (int e = 1; e < 8; ++e) if (acc[e] > l0) { l0 = acc[e]; e0 = e; }
        int e1 = -1; float l1 = -3e38f;
        #pragma unroll
        for (int e = 0; e < 8; ++e) if (e != e0 && acc[e] > l1) { l1 = acc[e]; e1 = e; }
        float pp = expf(l1 - l0);             // <= 1
        float g0 = 1.f / (1.f + pp);
        float g1 = pp / (1.f + pp);
        tok_e[t*2] = e0; tok_e[t*2+1] = e1;
        tok_g[t*2] = g0; tok_g[t*2+1] = g1;
        atomicAdd(&counts[e0], 1);
        atomicAdd(&counts[e1], 1);
    }
}

__global__ void init_kernel(int* __restrict__ counts, int* __restrict__ row2tok, int cap) {
    int i = blockIdx.x * blockDim.x + threadIdx.x;
    if (i < 8) counts[i] = 0;
    if (i < cap) row2tok[i] = -1;
}

__global__ void offsets_kernel(const int* __restrict__ counts, int* __restrict__ offsets,
                               int* __restrict__ cursor) {
    if (threadIdx.x == 0 && blockIdx.x == 0) {
        int off = 0;
        for (int e = 0; e < 8; ++e) {
            offsets[e] = off;
            cursor[e]  = off;
            off += ((counts[e] + 31) / 32) * 32;  // pad each segment to tile
        }
        offsets[8] = off;
    }
}

__global__ void fill_kernel(const int* __restrict__ tok_e, int* __restrict__ cursor,
                            int* __restrict__ row2tok, int* __restrict__ tok_row) {
    int t = blockIdx.x * blockDim.x + threadIdx.x;
    if (t >= TT) return;
    #pragma unroll
    for (int k = 0; k < 2; ++k) {
        int e = tok_e[t*2+k];
        int slot = atomicAdd(&cursor[e], 1);
        row2tok[slot] = t;
        tok_row[t*2+k] = slot;
    }
}

// ---------------- expert pass A: h = gelu(gather(xn) @ w1[e] + b1[e]) ----------------
// grid (CAP_ROWS/32, HID/64), block 256
__global__ void expert1_kernel(const float* __restrict__ xn, const float* __restrict__ w1,
                               const float* __restrict__ b1, const int* __restrict__ offsets,
                               const int* __restrict__ row2tok, float* __restrict__ h) {
    int r0 = blockIdx.x * 32;
    if (r0 >= offsets[8]) return;
    int e = 0;
    while (r0 >= offsets[e + 1]) ++e;
    int n0 = blockIdx.y * 64;
    __shared__ float As[32][33];
    __shared__ float Bs[32][65];
    __shared__ int toks[32];
    int tid = threadIdx.x;
    if (tid < 32) toks[tid] = row2tok[r0 + tid];
    __syncthreads();
    const float* W = w1 + (size_t)e * DIMC * HID;
    int ty = tid / 16, tx = tid % 16;
    float acc[2][4] = {};
    for (int k0 = 0; k0 < DIMC; k0 += 32) {
        {
            int c = tid % 32, rr = tid / 32;
            #pragma unroll
            for (int p = 0; p < 4; ++p) {
                int r = rr + p * 8;
                int tok = toks[r];
                As[r][c] = (tok >= 0) ? xn[(size_t)tok * DIMC + k0 + c] : 0.f;
            }
        }
        {
            int c = tid % 64, rr = tid / 64;
            #pragma unroll
            for (int p = 0; p < 8; ++p) {
                int r = rr + p * 4;
                Bs[r][c] = W[(size_t)(k0 + r) * HID + n0 + c];
            }
        }
        __syncthreads();
        #pragma unroll
        for (int k = 0; k < 32; ++k) {
            float a0 = As[ty*2+0][k];
            float a1 = As[ty*2+1][k];
            #pragma unroll
            for (int j = 0; j < 4; ++j) {
                float bj = Bs[k][tx*4+j];
                acc[0][j] += a0 * bj;
                acc[1][j] += a1 * bj;
            }
        }
        __syncthreads();
    }
    const float* bb = b1 + (size_t)e * HID;
    #pragma unroll
    for (int i = 0; i < 2; ++i) {
        int r = r0 + ty*2 + i;
        #pragma unroll
        for (int j = 0; j < 4; ++j) {
            int c = n0 + tx*4 + j;
            float v = acc[i][j] + bb[c];
            v = 0.5f * v * (1.f + erff(v * 0.70710678f));  // exact gelu
            h[(size_t)r * HID + c] = v;
        }
    }
}

// ---------------- expert pass B: y = h @ w2[e] ----------------
// grid (CAP_ROWS/32, DIMC/64), block 256
__global__ void expert2_kernel(const float* __restrict__ h, const float* __restrict__ w2,
                               const int* __restrict__ offsets, float* __restrict__ y) {
    int r0 = blockIdx.x * 32;
    if (r0 >= offsets[8]) return;
    int e = 0;
    while (r0 >= offsets[e + 1]) ++e;
    int n0 = blockIdx.y * 64;
    __shared__ float As[32][33];
    __shared__ float Bs[32][65];
    int tid = threadIdx.x;
    const float* W = w2 + (size_t)e * HID * DIMC;
    int ty = tid / 16, tx = tid % 16;
    float acc[2][4] = {};
    for (int k0 = 0; k0 < HID; k0 += 32) {
        {
            int c = tid % 32, rr = tid / 32;
            #pragma unroll
            for (int p = 0; p < 4; ++p) {
                int r = rr + p * 8;
                As[r][c] = h[(size_t)(r0 + r) * HID + k0 + c];
            }
        }
        {
            int c = tid % 64, rr = tid / 64;
            #pragma unroll
            for (int p = 0; p < 8; ++p) {
                int r = rr + p * 4;
                Bs[r][c] = W[(size_t)(k0 + r) * DIMC + n0 + c];
            }
        }
        __syncthreads();
        #pragma unroll
        for (int k = 0; k < 32; ++k) {
            float a0 = As[ty*2+0][k];
            float a1 = As[ty*2+1][k];
            #pragma unroll
            for (int j = 0; j < 4; ++j) {
                float bj = Bs[k][tx*4+j];
                acc[0][j] += a0 * bj;
                acc[1][j] += a1 * bj;
            }
        }
        __syncthreads();
    }
    #pragma unroll
    for (int i = 0; i < 2; ++i) {
        int r = r0 + ty*2 + i;
        #pragma unroll
        for (int j = 0; j < 4; ++j) {
            int c = n0 + tx*4 + j;
            y[(size_t)r * DIMC + c] = acc[i][j];
        }
    }
}

// ---------------- combine: out = x_res + sum_k g_k*(y[row_k] + b2[e_k]) ----------------
__global__ void combine_kernel(const float* __restrict__ x_res, const float* __restrict__ y,
                               const float* __restrict__ b2, const int* __restrict__ tok_e,
                               const float* __restrict__ tok_g, const int* __restrict__ tok_row,
                               float* __restrict__ out) {
    int t = blockIdx.x;
    int c = blockIdx.y * 256 + threadIdx.x;
    int e0 = tok_e[t*2], e1 = tok_e[t*2+1];
    float g0 = tok_g[t*2], g1 = tok_g[t*2+1];
    int r0 = tok_row[t*2], r1 = tok_row[t*2+1];
    float v = x_res[(size_t)t * DIMC + c]
            + g0 * (y[(size_t)r0 * DIMC + c] + b2[(size_t)e0 * DIMC + c])
            + g1 * (y[(size_t)r1 * DIMC + c] + b2[(size_t)e1 * DIMC + c]);
    out[(size_t)t * DIMC + c] = v;
}

extern "C" void kernel_launch(void* const* d_in, const int* in_sizes, int n_in,
                              void* d_out, int out_size, void* d_ws, size_t ws_size,
                              hipStream_t stream) {
    const float* x      = (const float*)d_in[0];
    const float* ln1_g  = (const float*)d_in[1];
    const float* ln1_b  = (const float*)d_in[2];
    const float* qkv_w  = (const float*)d_in[3];
    const float* qkv_b  = (const float*)d_in[4];
    const float* proj_w = (const float*)d_in[5];
    const float* proj_b = (const float*)d_in[6];
    const float* ln2_g  = (const float*)d_in[7];
    const float* ln2_b  = (const float*)d_in[8];
    const float* gate_w = (const float*)d_in[9];
    const float* w1     = (const float*)d_in[10];
    const float* b1     = (const float*)d_in[11];
    const float* w2     = (const float*)d_in[12];
    const float* b2     = (const float*)d_in[13];
    float* out = (float*)d_out;

    char* p = (char*)d_ws;
    auto alloc = [&](size_t nbytes) {
        void* r = (void*)p;
        p += (nbytes + 255) & ~(size_t)255;
        return r;
    };
    float* xn1     = (float*)alloc((size_t)TT * 768 * 4);
    float* qkv     = (float*)alloc((size_t)TT * 2304 * 4);
    float* attn_o  = (float*)alloc((size_t)TT * 768 * 4);
    float* x_res   = (float*)alloc((size_t)TT * 768 * 4);
    float* xn2     = (float*)alloc((size_t)TT * 768 * 4);
    float* h       = (float*)alloc((size_t)CAP_ROWS * HID * 4);
    float* y       = (float*)alloc((size_t)CAP_ROWS * 768 * 4);
    float* tok_g   = (float*)alloc((size_t)2 * TT * 4);
    int*   tok_e   = (int*)alloc((size_t)2 * TT * 4);
    int*   tok_row = (int*)alloc((size_t)2 * TT * 4);
    int*   row2tok = (int*)alloc((size_t)CAP_ROWS * 4);
    int*   counts  = (int*)alloc(32 * 4);
    int*   offsets = (int*)alloc(32 * 4);
    int*   cursor  = (int*)alloc(32 * 4);

    init_kernel<<<(CAP_ROWS + 255) / 256, 256, 0, stream>>>(counts, row2tok, CAP_ROWS);

    ln_kernel<<<TT, 256, 0, stream>>>(x, ln1_g, ln1_b, xn1);

    gemm_f32<<<dim3(TT / 32, 2304 / 64), 256, 0, stream>>>(xn1, qkv_w, qkv_b, nullptr, qkv,
                                                           TT, 2304, 768);

    attn_kernel<<<dim3(BB * HEADS, (NN + 31) / 32), 256, 0, stream>>>(qkv, attn_o);

    gemm_f32<<<dim3(TT / 32, 768 / 64), 256, 0, stream>>>(attn_o, proj_w, proj_b, x, x_res,
                                                          TT, 768, 768);

    ln_kernel<<<TT, 256, 0, stream>>>(x_res, ln2_g, ln2_b, xn2);

    gate_kernel<<<TT, 64, 0, stream>>>(xn2, gate_w, tok_e, tok_g, counts);

    offsets_kernel<<<1, 64, 0, stream>>>(counts, offsets, cursor);

    fill_kernel<<<(TT + 255) / 256, 256, 0, stream>>>(tok_e, cursor, row2tok, tok_row);

    expert1_kernel<<<dim3(CAP_ROWS / 32, HID / 64), 256, 0, stream>>>(xn2, w1, b1, offsets,
                                                                      row2tok, h);

    expert2_kernel<<<dim3(CAP_ROWS / 32, 768 / 64), 256, 0, stream>>>(h, w2, offsets, y);

    combine_kernel<<<dim3(TT, 3), 256, 0, stream>>>(x_res, y, b2, tok_e, tok_g, tok_row, out);
}

// Round 3
// 728.938 us; speedup vs baseline: 2.1494x; 2.1494x over previous
//
#include <hip/hip_runtime.h>
#include <hip/hip_bf16.h>
#include <math.h>

#define DIMC 768
#define HEADS 12
#define HD 64
#define EXPERTS 8
#define HID 3072
#define BB 8
#define NN 196
#define TT (BB*NN)      // 1568
#define CAP_ROWS 3648   // 2*TT + 8*64 headroom, multiple of 64
#define LN_EPS 1e-5f

typedef float f32x4_t __attribute__((ext_vector_type(4)));
typedef short bf16x8_t __attribute__((ext_vector_type(8)));

__device__ __forceinline__ unsigned short f2bf(float f) {
    unsigned int u = __float_as_uint(f);
    u += 0x7FFFu + ((u >> 16) & 1u);   // round-to-nearest-even
    return (unsigned short)(u >> 16);
}

// ---------------- LayerNorm: one block per token, 256 threads, D=768 ----------------
__global__ void ln_kernel(const float* __restrict__ x, const float* __restrict__ g,
                          const float* __restrict__ b, float* __restrict__ out_f,
                          unsigned short* __restrict__ out_bf) {
    int t = blockIdx.x;
    const float* xr = x + (size_t)t * DIMC;
    int tid = threadIdx.x;
    float v0 = xr[tid], v1 = xr[tid + 256], v2 = xr[tid + 512];
    __shared__ float red[256];
    red[tid] = v0 + v1 + v2;
    __syncthreads();
    for (int off = 128; off > 0; off >>= 1) {
        if (tid < off) red[tid] += red[tid + off];
        __syncthreads();
    }
    float mu = red[0] * (1.0f / DIMC);
    __syncthreads();
    float d0 = v0 - mu, d1 = v1 - mu, d2 = v2 - mu;
    red[tid] = d0*d0 + d1*d1 + d2*d2;
    __syncthreads();
    for (int off = 128; off > 0; off >>= 1) {
        if (tid < off) red[tid] += red[tid + off];
        __syncthreads();
    }
    float rstd = rsqrtf(red[0] * (1.0f / DIMC) + LN_EPS);
    float o0 = d0 * rstd * g[tid]       + b[tid];
    float o1 = d1 * rstd * g[tid + 256] + b[tid + 256];
    float o2 = d2 * rstd * g[tid + 512] + b[tid + 512];
    if (out_f) {
        float* o = out_f + (size_t)t * DIMC;
        o[tid] = o0; o[tid + 256] = o1; o[tid + 512] = o2;
    }
    if (out_bf) {
        unsigned short* o = out_bf + (size_t)t * DIMC;
        o[tid] = f2bf(o0); o[tid + 256] = f2bf(o1); o[tid + 512] = f2bf(o2);
    }
}

// ---------------- generic fp32 tiled GEMM (kept for pre-gate path this round) ----------------
__global__ void gemm_f32(const float* __restrict__ A, const float* __restrict__ B,
                         const float* __restrict__ bias, const float* __restrict__ res,
                         float* __restrict__ C, int M, int N, int K) {
    __shared__ float As[32][33];
    __shared__ float Bs[32][65];
    int m0 = blockIdx.x * 32;
    int n0 = blockIdx.y * 64;
    int tid = threadIdx.x;
    int ty = tid / 16, tx = tid % 16;
    float acc[2][4] = {};
    for (int k0 = 0; k0 < K; k0 += 32) {
        {
            int c = tid % 32, rr = tid / 32;
            #pragma unroll
            for (int p = 0; p < 4; ++p) {
                int r = rr + p * 8;
                As[r][c] = A[(size_t)(m0 + r) * K + k0 + c];
            }
        }
        {
            int c = tid % 64, rr = tid / 64;
            #pragma unroll
            for (int p = 0; p < 8; ++p) {
                int r = rr + p * 4;
                Bs[r][c] = B[(size_t)(k0 + r) * N + n0 + c];
            }
        }
        __syncthreads();
        #pragma unroll
        for (int k = 0; k < 32; ++k) {
            float a0 = As[ty*2+0][k];
            float a1 = As[ty*2+1][k];
            #pragma unroll
            for (int j = 0; j < 4; ++j) {
                float bj = Bs[k][tx*4+j];
                acc[0][j] += a0 * bj;
                acc[1][j] += a1 * bj;
            }
        }
        __syncthreads();
    }
    #pragma unroll
    for (int i = 0; i < 2; ++i) {
        int r = m0 + ty*2 + i;
        #pragma unroll
        for (int j = 0; j < 4; ++j) {
            int c = n0 + tx*4 + j;
            float v = acc[i][j] + bias[c];
            if (res) v += res[(size_t)r * N + c];
            C[(size_t)r * N + c] = v;
        }
    }
}

// ---------------- attention: grid (B*H, ceil(N/32)), block 256 (fp32) ----------------
__global__ void attn_kernel(const float* __restrict__ qkv, float* __restrict__ o) {
    int bh = blockIdx.x;
    int b = bh / HEADS, h = bh % HEADS;
    int i0 = blockIdx.y * 32;
    const float* base = qkv + (size_t)b * NN * 2304;
    __shared__ float qs[32][64];
    __shared__ float ps[32][200];
    int tid = threadIdx.x;
    for (int idx = tid; idx < 32 * 64; idx += 256) {
        int i = idx / 64, d = idx % 64;
        int n = i0 + i;
        qs[i][d] = (n < NN) ? base[(size_t)n * 2304 + h * 64 + d] : 0.f;
    }
    __syncthreads();
    for (int idx = tid; idx < 32 * NN; idx += 256) {
        int i = idx / NN, j = idx % NN;
        const float* kr = base + (size_t)j * 2304 + 768 + h * 64;
        float s = 0.f;
        #pragma unroll
        for (int d = 0; d < 64; ++d) s += qs[i][d] * kr[d];
        ps[i][j] = s * 0.125f;
    }
    __syncthreads();
    {
        int i = tid / 8, l = tid % 8;
        float mx = -1e30f;
        for (int j = l; j < NN; j += 8) mx = fmaxf(mx, ps[i][j]);
        #pragma unroll
        for (int off = 4; off > 0; off >>= 1) mx = fmaxf(mx, __shfl_xor(mx, off, 8));
        float sum = 0.f;
        for (int j = l; j < NN; j += 8) { float e = expf(ps[i][j] - mx); ps[i][j] = e; sum += e; }
        #pragma unroll
        for (int off = 4; off > 0; off >>= 1) sum += __shfl_xor(sum, off, 8);
        float inv = 1.f / sum;
        for (int j = l; j < NN; j += 8) ps[i][j] *= inv;
    }
    __syncthreads();
    for (int idx = tid; idx < 32 * 64; idx += 256) {
        int i = idx / 64, d = idx % 64;
        int n = i0 + i;
        if (n >= NN) continue;
        float s = 0.f;
        for (int j = 0; j < NN; ++j) s += ps[i][j] * base[(size_t)j * 2304 + 1536 + h * 64 + d];
        o[((size_t)(b * NN + n)) * DIMC + h * 64 + d] = s;
    }
}

// ---------------- gate: one wave per token (fp32 — expert choice must match ref) ----------------
__global__ void gate_kernel(const float* __restrict__ xn, const float* __restrict__ gw,
                            int* __restrict__ tok_e, float* __restrict__ tok_g,
                            int* __restrict__ counts) {
    int t = blockIdx.x;
    int lane = threadIdx.x;  // 64
    float acc[8] = {};
    const float* xr = xn + (size_t)t * DIMC;
    for (int i = lane; i < DIMC; i += 64) {
        float xi = xr[i];
        const float* gr = gw + (size_t)i * 8;
        #pragma unroll
        for (int e = 0; e < 8; ++e) acc[e] += xi * gr[e];
    }
    #pragma unroll
    for (int e = 0; e < 8; ++e) {
        #pragma unroll
        for (int off = 32; off > 0; off >>= 1) acc[e] += __shfl_down(acc[e], off, 64);
    }
    if (lane == 0) {
        int e0 = 0; float l0 = acc[0];
        #pragma unroll
        for (int e = 1; e < 8; ++e) if (acc[e] > l0) { l0 = acc[e]; e0 = e; }
        int e1 = -1; float l1 = -3e38f;
        #pragma unroll
        for (int e = 0; e < 8; ++e) if (e != e0 && acc[e] > l1) { l1 = acc[e]; e1 = e; }
        float pp = expf(l1 - l0);
        float g0 = 1.f / (1.f + pp);
        float g1 = pp / (1.f + pp);
        tok_e[t*2] = e0; tok_e[t*2+1] = e1;
        tok_g[t*2] = g0; tok_g[t*2+1] = g1;
        atomicAdd(&counts[e0], 1);
        atomicAdd(&counts[e1], 1);
    }
}

__global__ void init_kernel(int* __restrict__ counts, int* __restrict__ row2tok, int cap) {
    int i = blockIdx.x * blockDim.x + threadIdx.x;
    if (i < 8) counts[i] = 0;
    if (i < cap) row2tok[i] = -1;
}

__global__ void offsets_kernel(const int* __restrict__ counts, int* __restrict__ offsets,
                               int* __restrict__ cursor) {
    if (threadIdx.x == 0 && blockIdx.x == 0) {
        int off = 0;
        for (int e = 0; e < 8; ++e) {
            offsets[e] = off;
            cursor[e]  = off;
            off += ((counts[e] + 63) / 64) * 64;  // pad each segment to BM=64
        }
        offsets[8] = off;
    }
}

__global__ void fill_kernel(const int* __restrict__ tok_e, int* __restrict__ cursor,
                            int* __restrict__ row2tok, int* __restrict__ tok_row) {
    int t = blockIdx.x * blockDim.x + threadIdx.x;
    if (t >= TT) return;
    #pragma unroll
    for (int k = 0; k < 2; ++k) {
        int e = tok_e[t*2+k];
        int slot = atomicAdd(&cursor[e], 1);
        row2tok[slot] = t;
        tok_row[t*2+k] = slot;
    }
}

// ---------------- batched transpose + fp32->bf16: src [B][R][C] -> dst [B][C][R] ----------------
// grid (C/64, R/64, B), block 256
__global__ void transpose_bf16(const float* __restrict__ src, unsigned short* __restrict__ dst,
                               int R, int C) {
    __shared__ float tile[64][65];
    const float* s = src + (size_t)blockIdx.z * R * C;
    unsigned short* d = dst + (size_t)blockIdx.z * R * C;
    int c0 = blockIdx.x * 64, r0 = blockIdx.y * 64;
    int tid = threadIdx.x;
    int tr = tid >> 4;            // 0..15
    int tc = (tid & 15) * 4;      // 0..60
    #pragma unroll
    for (int p = 0; p < 4; ++p) {
        int r = tr + p * 16;
        const float4 v = *(const float4*)(s + (size_t)(r0 + r) * C + c0 + tc);
        tile[r][tc+0] = v.x; tile[r][tc+1] = v.y; tile[r][tc+2] = v.z; tile[r][tc+3] = v.w;
    }
    __syncthreads();
    #pragma unroll
    for (int p = 0; p < 4; ++p) {
        int c = tr + p * 16;      // local col -> dst row
        ushort4 o;
        o.x = f2bf(tile[tc+0][c]);
        o.y = f2bf(tile[tc+1][c]);
        o.z = f2bf(tile[tc+2][c]);
        o.w = f2bf(tile[tc+3][c]);
        *(ushort4*)(d + (size_t)(c0 + c) * R + r0 + tc) = o;
    }
}

// ---------------- grouped bf16 MFMA GEMM ----------------
// C[rows][N] = act( gather(A)[rows][K] @ Bt[e][N][K]^T + bias[e][N] )
// BM=BN=BK=64, 256 threads = 4 waves (2x2), each wave 32x32 via 2x2 16x16x32 MFMA.
// grid (CAP_ROWS/64, N/64). LDS tiles XOR-swizzled: byte ^= (row&7)<<4.
template<int GATHER, int GELU, int OUT_BF16>
__global__ void mfma_gemm_grouped(const unsigned short* __restrict__ A,
                                  const unsigned short* __restrict__ Bt,
                                  const float* __restrict__ bias,
                                  const int* __restrict__ offsets,
                                  const int* __restrict__ row2tok,
                                  void* __restrict__ Cout,
                                  int N, int K) {
    __shared__ unsigned short As[64 * 64];
    __shared__ unsigned short Bs[64 * 64];
    __shared__ int toks[64];

    int r0 = blockIdx.x * 64;
    if (r0 >= offsets[8]) return;
    int e = 0;
    while (r0 >= offsets[e + 1]) ++e;
    int n0 = blockIdx.y * 64;
    int tid = threadIdx.x;
    if (GATHER && tid < 64) toks[tid] = row2tok[r0 + tid];
    __syncthreads();

    const unsigned short* Be = Bt + (size_t)e * N * K;

    int sr = tid >> 3;        // 0..31 (staging row, +32 second pass)
    int sq = tid & 7;         // 0..7  (16B chunk within 128B row)
    int lane = tid & 63;
    int wid = tid >> 6;
    int wm = (wid >> 1) * 32;
    int wn = (wid & 1) * 32;
    int colb_base = (lane >> 4) * 16;
    int lrow = lane & 15;

    f32x4_t acc[2][2] = {};

    for (int k0 = 0; k0 < K; k0 += 64) {
        #pragma unroll
        for (int p = 0; p < 2; ++p) {
            int r = sr + p * 32;
            int swz = (sq * 16) ^ ((r & 7) << 4);
            int4 va = {0, 0, 0, 0};
            if (GATHER) {
                int tok = toks[r];
                if (tok >= 0) va = *(const int4*)(A + (size_t)tok * K + k0 + sq * 8);
            } else {
                va = *(const int4*)(A + (size_t)(r0 + r) * K + k0 + sq * 8);
            }
            *(int4*)((char*)As + r * 128 + swz) = va;
            int4 vb = *(const int4*)(Be + (size_t)(n0 + r) * K + k0 + sq * 8);
            *(int4*)((char*)Bs + r * 128 + swz) = vb;
        }
        __syncthreads();
        #pragma unroll
        for (int kk = 0; kk < 2; ++kk) {
            int colb = kk * 64 + colb_base;
            bf16x8_t a[2], b[2];
            #pragma unroll
            for (int i = 0; i < 2; ++i) {
                int ra = wm + i * 16 + lrow;
                a[i] = *(const bf16x8_t*)((const char*)As + ra * 128 + (colb ^ ((ra & 7) << 4)));
                int rb = wn + i * 16 + lrow;
                b[i] = *(const bf16x8_t*)((const char*)Bs + rb * 128 + (colb ^ ((rb & 7) << 4)));
            }
            #pragma unroll
            for (int mi = 0; mi < 2; ++mi)
                #pragma unroll
                for (int ni = 0; ni < 2; ++ni)
                    acc[mi][ni] = __builtin_amdgcn_mfma_f32_16x16x32_bf16(
                        a[mi], b[ni], acc[mi][ni], 0, 0, 0);
        }
        __syncthreads();
    }

    #pragma unroll
    for (int mi = 0; mi < 2; ++mi) {
        #pragma unroll
        for (int ni = 0; ni < 2; ++ni) {
            int col = n0 + wn + ni * 16 + lrow;
            float bv = GELU ? bias[(size_t)e * N + col] : 0.f;
            #pragma unroll
            for (int j = 0; j < 4; ++j) {
                int row = r0 + wm + mi * 16 + (lane >> 4) * 4 + j;
                float v = acc[mi][ni][j] + bv;
                if (GELU) v = 0.5f * v * (1.f + erff(v * 0.70710678f));
                if (OUT_BF16)
                    ((unsigned short*)Cout)[(size_t)row * N + col] = f2bf(v);
                else
                    ((float*)Cout)[(size_t)row * N + col] = v;
            }
        }
    }
}

// ---------------- combine: out = x_res + sum_k g_k*(y[row_k] + b2[e_k]) ----------------
__global__ void combine_kernel(const float* __restrict__ x_res, const float* __restrict__ y,
                               const float* __restrict__ b2, const int* __restrict__ tok_e,
                               const float* __restrict__ tok_g, const int* __restrict__ tok_row,
                               float* __restrict__ out) {
    int t = blockIdx.x;
    int c = blockIdx.y * 256 + threadIdx.x;
    int e0 = tok_e[t*2], e1 = tok_e[t*2+1];
    float g0 = tok_g[t*2], g1 = tok_g[t*2+1];
    int r0 = tok_row[t*2], r1 = tok_row[t*2+1];
    float v = x_res[(size_t)t * DIMC + c]
            + g0 * (y[(size_t)r0 * DIMC + c] + b2[(size_t)e0 * DIMC + c])
            + g1 * (y[(size_t)r1 * DIMC + c] + b2[(size_t)e1 * DIMC + c]);
    out[(size_t)t * DIMC + c] = v;
}

extern "C" void kernel_launch(void* const* d_in, const int* in_sizes, int n_in,
                              void* d_out, int out_size, void* d_ws, size_t ws_size,
                              hipStream_t stream) {
    const float* x      = (const float*)d_in[0];
    const float* ln1_g  = (const float*)d_in[1];
    const float* ln1_b  = (const float*)d_in[2];
    const float* qkv_w  = (const float*)d_in[3];
    const float* qkv_b  = (const float*)d_in[4];
    const float* proj_w = (const float*)d_in[5];
    const float* proj_b = (const float*)d_in[6];
    const float* ln2_g  = (const float*)d_in[7];
    const float* ln2_b  = (const float*)d_in[8];
    const float* gate_w = (const float*)d_in[9];
    const float* w1     = (const float*)d_in[10];
    const float* b1     = (const float*)d_in[11];
    const float* w2     = (const float*)d_in[12];
    const float* b2     = (const float*)d_in[13];
    float* out = (float*)d_out;

    char* p = (char*)d_ws;
    auto alloc = [&](size_t nbytes) {
        void* r = (void*)p;
        p += (nbytes + 255) & ~(size_t)255;
        return r;
    };
    float*          xn1     = (float*)alloc((size_t)TT * DIMC * 4);
    float*          qkv     = (float*)alloc((size_t)TT * 2304 * 4);
    float*          attn_o  = (float*)alloc((size_t)TT * DIMC * 4);
    float*          x_res   = (float*)alloc((size_t)TT * DIMC * 4);
    float*          xn2_f   = (float*)alloc((size_t)TT * DIMC * 4);
    unsigned short* xn2_bf  = (unsigned short*)alloc((size_t)TT * DIMC * 2);
    unsigned short* h       = (unsigned short*)alloc((size_t)CAP_ROWS * HID * 2);
    float*          y       = (float*)alloc((size_t)CAP_ROWS * DIMC * 4);
    unsigned short* w1t     = (unsigned short*)alloc((size_t)EXPERTS * DIMC * HID * 2);
    unsigned short* w2t     = (unsigned short*)alloc((size_t)EXPERTS * DIMC * HID * 2);
    float*          tok_g   = (float*)alloc((size_t)2 * TT * 4);
    int*            tok_e   = (int*)alloc((size_t)2 * TT * 4);
    int*            tok_row = (int*)alloc((size_t)2 * TT * 4);
    int*            row2tok = (int*)alloc((size_t)CAP_ROWS * 4);
    int*            counts  = (int*)alloc(32 * 4);
    int*            offsets = (int*)alloc(32 * 4);
    int*            cursor  = (int*)alloc(32 * 4);

    init_kernel<<<(CAP_ROWS + 255) / 256, 256, 0, stream>>>(counts, row2tok, CAP_ROWS);

    // weight transposes (independent of activations)
    transpose_bf16<<<dim3(HID / 64, DIMC / 64, EXPERTS), 256, 0, stream>>>(w1, w1t, DIMC, HID);
    transpose_bf16<<<dim3(DIMC / 64, HID / 64, EXPERTS), 256, 0, stream>>>(w2, w2t, HID, DIMC);

    ln_kernel<<<TT, 256, 0, stream>>>(x, ln1_g, ln1_b, xn1, nullptr);

    gemm_f32<<<dim3(TT / 32, 2304 / 64), 256, 0, stream>>>(xn1, qkv_w, qkv_b, nullptr, qkv,
                                                           TT, 2304, 768);

    attn_kernel<<<dim3(BB * HEADS, (NN + 31) / 32), 256, 0, stream>>>(qkv, attn_o);

    gemm_f32<<<dim3(TT / 32, 768 / 64), 256, 0, stream>>>(attn_o, proj_w, proj_b, x, x_res,
                                                          TT, 768, 768);

    ln_kernel<<<TT, 256, 0, stream>>>(x_res, ln2_g, ln2_b, xn2_f, xn2_bf);

    gate_kernel<<<TT, 64, 0, stream>>>(xn2_f, gate_w, tok_e, tok_g, counts);

    offsets_kernel<<<1, 64, 0, stream>>>(counts, offsets, cursor);

    fill_kernel<<<(TT + 255) / 256, 256, 0, stream>>>(tok_e, cursor, row2tok, tok_row);

    mfma_gemm_grouped<1, 1, 1><<<dim3(CAP_ROWS / 64, HID / 64), 256, 0, stream>>>(
        xn2_bf, w1t, b1, offsets, row2tok, h, HID, DIMC);

    mfma_gemm_grouped<0, 0, 0><<<dim3(CAP_ROWS / 64, DIMC / 64), 256, 0, stream>>>(
        h, w2t, nullptr, offsets, row2tok, y, DIMC, HID);

    combine_kernel<<<dim3(TT, 3), 256, 0, stream>>>(x_res, y, b2, tok_e, tok_g, tok_row, out);
}